// Round 8
// baseline (561.018 us; speedup 1.0000x reference)
//
#include <hip/hip_runtime.h>
#include <hip/hip_bf16.h>
#include <math.h>

// q [8192,1024] f32, k [8192,1024] f32, v [8192,1024] f32
// scores = q@k^T; x = scores/||row|| * sqrt(8192); gated = gelu_exact(x); out = gated@v
//
// ws layout (~176 MiB):
//   [0,16M)    qb   bf16 8192x1024
//   [16M,32M)  kb   bf16 8192x1024
//   [32M,48M)  vbT  bf16 1024x8192
//   [48M,176M) scores/gated bf16 8192x8192 (in-place gelu)
//   [176M,+32K) sumsq f32 [8192]
//
// R7 (resubmit of R6 — infra failure, no data):
//     (1) prep fused into one launch (7 -> 4 launches; ~10us gap each);
//     (2) gemm1 = 128^2 2-barrier m97-class structure (3 blk/CU TLP) + the
//         R5-verified both-sides XOR slot swizzle (conflict-free LDS);
//     (3) gemm2/gelu unchanged controls.

#define MROWS 8192
#define DIN   1024
#define NBANK 8192
#define DOUT  1024

typedef float  f32x4  __attribute__((ext_vector_type(4)));
typedef __bf16 bf16x8 __attribute__((ext_vector_type(8)));

__device__ __forceinline__ float bf2f(unsigned short u) {
  union { unsigned int i; float f; } x; x.i = ((unsigned int)u) << 16; return x.f;
}
__device__ __forceinline__ unsigned short f2bf(float f) {
  union { float f; unsigned int i; } x; x.f = f;
  unsigned int u = x.i;
  unsigned int r = (u + 0x7fffu + ((u >> 16) & 1u)) >> 16;  // RNE
  return (unsigned short)r;
}

// ---------------- fused prep: cvt(q), cvt(k), transpose+cvt(v), zero(sumsq) --------
// blocks [0,8192): q cvt; [8192,16384): k cvt; [16384,24576): v transpose;
// [24576,24584): sumsq zero. 256 threads each.
__global__ void prep_kernel(const float* __restrict__ q, const float* __restrict__ k,
                            const float* __restrict__ v,
                            unsigned short* __restrict__ qb,
                            unsigned short* __restrict__ kb,
                            unsigned short* __restrict__ vbT,
                            float* __restrict__ sumsq) {
  __shared__ float tile[32][33];
  const int b = blockIdx.x;
  if (b < 16384) {
    const float* src = (b < 8192) ? q : k;
    unsigned short* dst = (b < 8192) ? qb : kb;
    int i = ((b & 8191) * 256 + threadIdx.x) * 4;
    float4 vv = *(const float4*)(src + i);
    ushort4 o;
    o.x = f2bf(vv.x); o.y = f2bf(vv.y); o.z = f2bf(vv.z); o.w = f2bf(vv.w);
    *(ushort4*)(dst + i) = o;
  } else if (b < 24576) {
    // transpose v[8192][1024] -> vbT[1024][8192]; 32x32 tiles
    int t = b - 16384;                 // 0..8191 = (R/32=256) * (C/32=32)
    int c0 = (t & 31) * 32;            // col tile in v
    int r0 = (t >> 5) * 32;            // row tile in v
    int tx = threadIdx.x & 31, ty = threadIdx.x >> 5;  // (32,8)
    for (int i = ty; i < 32; i += 8)
      tile[i][tx] = v[(size_t)(r0 + i) * DOUT + c0 + tx];
    __syncthreads();
    for (int i = ty; i < 32; i += 8)
      vbT[(size_t)(c0 + i) * NBANK + r0 + tx] = f2bf(tile[tx][i]);
  } else {
    int i = (b - 24576) * 256 + threadIdx.x;  // float4 index, 2048 total
    ((float4*)sumsq)[i] = make_float4(0.f, 0.f, 0.f, 0.f);
  }
}

// ---------------- GEMM1: scores = qb @ kb^T (bf16 out) + row sumsq atomics ----------
// 128x128 tile, 256 thr = 4 waves (2x2 of 64x64), BK=32, 16 KiB LDS, ~3 blk/CU.
// Both-sides XOR slot swizzle (R5-verified): conflict-free LDS frag reads.
__global__ __launch_bounds__(256, 2) void gemm1_kernel(
    const unsigned short* __restrict__ A, const unsigned short* __restrict__ B,
    unsigned short* __restrict__ C, float* __restrict__ sumsq) {
  __shared__ unsigned short As[128 * 32];
  __shared__ unsigned short Bs[128 * 32];
  const int K = DIN;

  const int tid  = threadIdx.x;
  const int lane = tid & 63;
  const int wave = tid >> 6;
  const int wm   = (wave >> 1) * 64;
  const int wn   = (wave & 1) * 64;
  const int quad = lane >> 4;
  const int l16  = lane & 15;

  // XCD swizzle: nwg = 64*64 = 4096, %8==0.
  const int flat = blockIdx.y * gridDim.x + blockIdx.x;
  const int nwg  = gridDim.x * gridDim.y;
  const int swz  = (flat & 7) * (nwg >> 3) + (flat >> 3);
  const size_t m0 = (size_t)(swz / gridDim.x) * 128;
  const size_t n0 = (size_t)(swz % gridDim.x) * 128;

  const int srow = tid >> 2;
  // source-side slot swizzle (rows srow and srow+64 share (row>>1)&3)
  const int scol = (((tid & 3) ^ ((tid >> 3) & 3))) * 8;
  const unsigned short* Ag0 = A + (m0 + srow) * (size_t)K + scol;
  const unsigned short* Ag1 = A + (m0 + srow + 64) * (size_t)K + scol;
  const unsigned short* Bg0 = B + (n0 + srow) * (size_t)K + scol;
  const unsigned short* Bg1 = B + (n0 + srow + 64) * (size_t)K + scol;

  unsigned short* AsW0 = As + tid * 8;
  unsigned short* AsW1 = As + 64 * 32 + tid * 8;
  unsigned short* BsW0 = Bs + tid * 8;
  unsigned short* BsW1 = Bs + 64 * 32 + tid * 8;

  // read-side swizzle: slot = quad ^ ((l16>>1)&3)
  const int sw = (l16 >> 1) & 3;
  const unsigned short* ArP = As + (wm + l16) * 32 + (quad ^ sw) * 8;
  const unsigned short* BrP = Bs + (wn + l16) * 32 + (quad ^ sw) * 8;

  f32x4 acc[4][4];
#pragma unroll
  for (int i = 0; i < 4; i++)
#pragma unroll
    for (int j = 0; j < 4; j++) {
      f32x4 z = {0.f, 0.f, 0.f, 0.f};
      acc[i][j] = z;
    }

  for (int k0 = 0; k0 < K; k0 += 32) {
    __builtin_amdgcn_global_load_lds(
        (const __attribute__((address_space(1))) unsigned int*)(Ag0 + k0),
        (__attribute__((address_space(3))) unsigned int*)AsW0, 16, 0, 0);
    __builtin_amdgcn_global_load_lds(
        (const __attribute__((address_space(1))) unsigned int*)(Ag1 + k0),
        (__attribute__((address_space(3))) unsigned int*)AsW1, 16, 0, 0);
    __builtin_amdgcn_global_load_lds(
        (const __attribute__((address_space(1))) unsigned int*)(Bg0 + k0),
        (__attribute__((address_space(3))) unsigned int*)BsW0, 16, 0, 0);
    __builtin_amdgcn_global_load_lds(
        (const __attribute__((address_space(1))) unsigned int*)(Bg1 + k0),
        (__attribute__((address_space(3))) unsigned int*)BsW1, 16, 0, 0);
    __syncthreads();

    bf16x8 af[4], bfr[4];
#pragma unroll
    for (int i = 0; i < 4; i++) af[i] = *(const bf16x8*)(ArP + i * 16 * 32);
#pragma unroll
    for (int j = 0; j < 4; j++) bfr[j] = *(const bf16x8*)(BrP + j * 16 * 32);
#pragma unroll
    for (int i = 0; i < 4; i++)
#pragma unroll
      for (int j = 0; j < 4; j++)
        acc[i][j] = __builtin_amdgcn_mfma_f32_16x16x32_bf16(af[i], bfr[j],
                                                            acc[i][j], 0, 0, 0);
    __syncthreads();
  }

  // Epilogue: bf16 scores + per-row sumsq atomics
#pragma unroll
  for (int i = 0; i < 4; i++)
#pragma unroll
    for (int r = 0; r < 4; r++) {
      size_t row = m0 + wm + i * 16 + quad * 4 + r;
      float s = 0.f;
#pragma unroll
      for (int j = 0; j < 4; j++) {
        float val = acc[i][j][r];
        s += val * val;
        C[row * (size_t)NBANK + n0 + wn + j * 16 + l16] = f2bf(val);
      }
      s += __shfl_xor(s, 1);
      s += __shfl_xor(s, 2);
      s += __shfl_xor(s, 4);
      s += __shfl_xor(s, 8);
      if (l16 == 0) atomicAdd(&sumsq[row], s);
    }
}

// ---------------- in-place exact GELU(x * sqrt(N/sumsq[row])) ----------------
__global__ void gelu_kernel(unsigned short* __restrict__ S,
                            const float* __restrict__ sumsq) {
  const size_t total = (size_t)MROWS * NBANK / 8;  // uint4 units
  for (size_t u = (size_t)blockIdx.x * 256 + threadIdx.x; u < total;
       u += (size_t)gridDim.x * 256) {
    size_t idx = u * 8;
    int row = (int)(idx >> 13);
    float sc = sqrtf((float)NBANK / sumsq[row]);
    uint4 vv = *(const uint4*)(S + idx);
    unsigned int w[4] = {vv.x, vv.y, vv.z, vv.w};
#pragma unroll
    for (int e = 0; e < 4; e++) {
      float x0 = bf2f((unsigned short)(w[e] & 0xffffu)) * sc;
      float x1 = bf2f((unsigned short)(w[e] >> 16)) * sc;
      float g0 = 0.5f * x0 * (1.0f + erff(x0 * 0.70710678118654752f));
      float g1 = 0.5f * x1 * (1.0f + erff(x1 * 0.70710678118654752f));
      w[e] = (unsigned int)f2bf(g0) | ((unsigned int)f2bf(g1) << 16);
    }
    uint4 o; o.x = w[0]; o.y = w[1]; o.z = w[2]; o.w = w[3];
    *(uint4*)(S + idx) = o;
  }
}

// ---------------- GEMM2: out = gated @ vbT^T, 128x128 tile, NO split-K --------------
// m97-class structure + both-sides LDS XOR swizzle (unchanged control arm).
__global__ __launch_bounds__(256, 4) void gemm2_kernel(
    const unsigned short* __restrict__ A,   // gated [8192][8192]
    const unsigned short* __restrict__ B,   // vbT   [1024][8192]
    float* __restrict__ C) {                // out   [8192][1024]
  __shared__ unsigned short As[128 * 32];
  __shared__ unsigned short Bs[128 * 32];
  const int K = NBANK, ldc = DOUT;

  const int tid  = threadIdx.x;
  const int lane = tid & 63;
  const int wave = tid >> 6;
  const int wm   = (wave >> 1) * 64;
  const int wn   = (wave & 1) * 64;
  const int quad = lane >> 4;
  const int l16  = lane & 15;

  // XCD swizzle: nwg = 8*64 = 512, %8==0.
  const int flat = blockIdx.y * gridDim.x + blockIdx.x;
  const int nwg  = gridDim.x * gridDim.y;
  const int swz  = (flat & 7) * (nwg >> 3) + (flat >> 3);
  const size_t m0 = (size_t)(swz / gridDim.x) * 128;
  const size_t n0 = (size_t)(swz % gridDim.x) * 128;

  const int srow = tid >> 2;
  const int scol = (((tid & 3) ^ ((tid >> 3) & 3))) * 8;
  const unsigned short* Ag0 = A + (m0 + srow) * (size_t)K + scol;
  const unsigned short* Ag1 = A + (m0 + srow + 64) * (size_t)K + scol;
  const unsigned short* Bg0 = B + (n0 + srow) * (size_t)K + scol;
  const unsigned short* Bg1 = B + (n0 + srow + 64) * (size_t)K + scol;

  unsigned short* AsW0 = As + tid * 8;
  unsigned short* AsW1 = As + 64 * 32 + tid * 8;
  unsigned short* BsW0 = Bs + tid * 8;
  unsigned short* BsW1 = Bs + 64 * 32 + tid * 8;

  const int sw = (l16 >> 1) & 3;
  const unsigned short* ArP = As + (wm + l16) * 32 + (quad ^ sw) * 8;
  const unsigned short* BrP = Bs + (wn + l16) * 32 + (quad ^ sw) * 8;

  f32x4 acc[4][4];
#pragma unroll
  for (int i = 0; i < 4; i++)
#pragma unroll
    for (int j = 0; j < 4; j++) {
      f32x4 z = {0.f, 0.f, 0.f, 0.f};
      acc[i][j] = z;
    }

  for (int k0 = 0; k0 < K; k0 += 32) {
    __builtin_amdgcn_global_load_lds(
        (const __attribute__((address_space(1))) unsigned int*)(Ag0 + k0),
        (__attribute__((address_space(3))) unsigned int*)AsW0, 16, 0, 0);
    __builtin_amdgcn_global_load_lds(
        (const __attribute__((address_space(1))) unsigned int*)(Ag1 + k0),
        (__attribute__((address_space(3))) unsigned int*)AsW1, 16, 0, 0);
    __builtin_amdgcn_global_load_lds(
        (const __attribute__((address_space(1))) unsigned int*)(Bg0 + k0),
        (__attribute__((address_space(3))) unsigned int*)BsW0, 16, 0, 0);
    __builtin_amdgcn_global_load_lds(
        (const __attribute__((address_space(1))) unsigned int*)(Bg1 + k0),
        (__attribute__((address_space(3))) unsigned int*)BsW1, 16, 0, 0);
    __syncthreads();

    bf16x8 af[4], bfr[4];
#pragma unroll
    for (int i = 0; i < 4; i++) af[i] = *(const bf16x8*)(ArP + i * 16 * 32);
#pragma unroll
    for (int j = 0; j < 4; j++) bfr[j] = *(const bf16x8*)(BrP + j * 16 * 32);
#pragma unroll
    for (int i = 0; i < 4; i++)
#pragma unroll
      for (int j = 0; j < 4; j++)
        acc[i][j] = __builtin_amdgcn_mfma_f32_16x16x32_bf16(af[i], bfr[j],
                                                            acc[i][j], 0, 0, 0);
    __syncthreads();
  }

#pragma unroll
  for (int i = 0; i < 4; i++)
#pragma unroll
    for (int j = 0; j < 4; j++)
#pragma unroll
      for (int r = 0; r < 4; r++) {
        size_t row = m0 + wm + i * 16 + quad * 4 + r;
        size_t col = n0 + wn + j * 16 + l16;
        C[row * (size_t)ldc + col] = acc[i][j][r];
      }
}

extern "C" void kernel_launch(void* const* d_in, const int* in_sizes, int n_in,
                              void* d_out, int out_size, void* d_ws, size_t ws_size,
                              hipStream_t stream) {
  const float* q = (const float*)d_in[0];
  const float* k = (const float*)d_in[1];
  const float* v = (const float*)d_in[2];
  float* out = (float*)d_out;

  char* ws = (char*)d_ws;
  const size_t MB = 1024ull * 1024ull;
  unsigned short* qb     = (unsigned short*)(ws);
  unsigned short* kb     = (unsigned short*)(ws + 16 * MB);
  unsigned short* vbT    = (unsigned short*)(ws + 32 * MB);
  unsigned short* scores = (unsigned short*)(ws + 48 * MB);
  float*          scale  = (float*)(ws + 176 * MB);  // sumsq

  // 1) fused prep (cvt q, cvt k, transpose v, zero sumsq)
  prep_kernel<<<24584, 256, 0, stream>>>(q, k, v, qb, kb, vbT, scale);

  // 2) gemm1: 128^2 tiles, grid 64x64
  gemm1_kernel<<<dim3(NBANK / 128, MROWS / 128), 256, 0, stream>>>(qb, kb, scores,
                                                                   scale);

  // 3) gelu (scale folded in)
  gelu_kernel<<<4096, 256, 0, stream>>>(scores, scale);

  // 4) gemm2
  gemm2_kernel<<<dim3(DOUT / 128, MROWS / 128), 256, 0, stream>>>(scores, vbT, out);
}

// Round 9
// 506.242 us; speedup vs baseline: 1.1082x; 1.1082x over previous
//
#include <hip/hip_runtime.h>
#include <hip/hip_bf16.h>
#include <math.h>

// q [8192,1024] f32, k [8192,1024] f32, v [8192,1024] f32
// scores = q@k^T; x = scores/||row|| * sqrt(8192); gated = gelu(x); out = gated@v
//
// ws layout (~176 MiB):
//   [0,16M)    qb   bf16 8192x1024
//   [16M,32M)  kb   bf16 8192x1024
//   [32M,48M)  vbT  bf16 1024x8192
//   [48M,176M) scores/gated bf16 8192x8192 (in-place gelu)
//   [176M,+32K) sumsq f32 [8192]
//
// R9: (1) gemm1 reverted to R5 measured-best (256^2 4-phase, 210us);
//     (2) gelu: erf -> tanh-form (x*sigmoid(2u), 5 VALU + 2 trans vs ~25 VALU;
//         |err|<=3e-4 on gated -> ~4e-5 on out, negligible vs 0.0078 absmax);
//     (3) prep fused + gemm2 unchanged (controls).

#define MROWS 8192
#define DIN   1024
#define NBANK 8192
#define DOUT  1024

typedef float  f32x4  __attribute__((ext_vector_type(4)));
typedef __bf16 bf16x8 __attribute__((ext_vector_type(8)));

__device__ __forceinline__ float bf2f(unsigned short u) {
  union { unsigned int i; float f; } x; x.i = ((unsigned int)u) << 16; return x.f;
}
__device__ __forceinline__ unsigned short f2bf(float f) {
  union { float f; unsigned int i; } x; x.f = f;
  unsigned int u = x.i;
  unsigned int r = (u + 0x7fffu + ((u >> 16) & 1u)) >> 16;  // RNE
  return (unsigned short)r;
}

// ---------------- fused prep: cvt(q), cvt(k), transpose+cvt(v), zero(sumsq) --------
__global__ void prep_kernel(const float* __restrict__ q, const float* __restrict__ k,
                            const float* __restrict__ v,
                            unsigned short* __restrict__ qb,
                            unsigned short* __restrict__ kb,
                            unsigned short* __restrict__ vbT,
                            float* __restrict__ sumsq) {
  __shared__ float tile[32][33];
  const int b = blockIdx.x;
  if (b < 16384) {
    const float* src = (b < 8192) ? q : k;
    unsigned short* dst = (b < 8192) ? qb : kb;
    int i = ((b & 8191) * 256 + threadIdx.x) * 4;
    float4 vv = *(const float4*)(src + i);
    ushort4 o;
    o.x = f2bf(vv.x); o.y = f2bf(vv.y); o.z = f2bf(vv.z); o.w = f2bf(vv.w);
    *(ushort4*)(dst + i) = o;
  } else if (b < 24576) {
    int t = b - 16384;
    int c0 = (t & 31) * 32;
    int r0 = (t >> 5) * 32;
    int tx = threadIdx.x & 31, ty = threadIdx.x >> 5;
    for (int i = ty; i < 32; i += 8)
      tile[i][tx] = v[(size_t)(r0 + i) * DOUT + c0 + tx];
    __syncthreads();
    for (int i = ty; i < 32; i += 8)
      vbT[(size_t)(c0 + i) * NBANK + r0 + tx] = f2bf(tile[tx][i]);
  } else {
    int i = (b - 24576) * 256 + threadIdx.x;
    ((float4*)sumsq)[i] = make_float4(0.f, 0.f, 0.f, 0.f);
  }
}

// ============================================================================
// 256x256 4-phase GEMM core (R5 measured-best for gemm1: 210us, conflicts 0).
// 512 thr = 8 waves (2M x 4N), per-wave 128x64, BK=64 (2 K-half sub-buffers),
// both-sides XOR slot swizzle, counted vmcnt(4), setprio around MFMA.
// ============================================================================

__device__ __forceinline__ void stage_half(const unsigned short* src, int ld,
                                           unsigned short* dstbase, int tid) {
  __builtin_amdgcn_global_load_lds(
      (const __attribute__((address_space(1))) unsigned int*)src,
      (__attribute__((address_space(3))) unsigned int*)(dstbase + tid * 8), 16, 0, 0);
  __builtin_amdgcn_global_load_lds(
      (const __attribute__((address_space(1))) unsigned int*)(src + (size_t)128 * ld),
      (__attribute__((address_space(3))) unsigned int*)(dstbase + 4096 + tid * 8), 16,
      0, 0);
}

__device__ __forceinline__ void read4(const unsigned short* base, bf16x8 f[4]) {
#pragma unroll
  for (int i = 0; i < 4; ++i) f[i] = *(const bf16x8*)(base + i * 512);
}

__device__ __forceinline__ void mfma16(const bf16x8 a[4], const bf16x8 b[4],
                                       f32x4 (&acc)[8][4], int mh) {
#pragma unroll
  for (int m = 0; m < 4; ++m)
#pragma unroll
    for (int n = 0; n < 4; ++n)
      acc[mh * 4 + m][n] = __builtin_amdgcn_mfma_f32_16x16x32_bf16(
          a[m], b[n], acc[mh * 4 + m][n], 0, 0, 0);
}

__device__ __forceinline__ void gemm_core(const unsigned short* __restrict__ Ap,
                                          const unsigned short* __restrict__ Bp,
                                          int lda, int ldb, int nkt,
                                          unsigned short* As, unsigned short* Bs,
                                          f32x4 (&acc)[8][4]) {
  const int tid  = threadIdx.x;
  const int lane = tid & 63;
  const int wm   = (tid >> 6) >> 2;  // 0..1
  const int wn   = (tid >> 6) & 3;   // 0..3
  const int quad = lane >> 4;
  const int l16  = lane & 15;
  // read-side swizzle: slot = quad ^ ((row>>1)&3)
  const int sw   = (l16 >> 1) & 3;
  const int aoff = (wm * 128 + l16) * 32 + (quad ^ sw) * 8;
  const int boff = (wn * 64 + l16) * 32 + (quad ^ sw) * 8;

  // source-side swizzle: slot = (tid&3) ^ ((row>>1)&3)
  const int gslot = (tid & 3) ^ ((tid >> 3) & 3);
  const unsigned short* Ag = Ap + (size_t)(tid >> 2) * lda + gslot * 8;
  const unsigned short* Bg = Bp + (size_t)(tid >> 2) * ldb + gslot * 8;

#pragma unroll
  for (int i = 0; i < 8; ++i)
#pragma unroll
    for (int j = 0; j < 4; ++j) {
      f32x4 z = {0.f, 0.f, 0.f, 0.f};
      acc[i][j] = z;
    }

  stage_half(Ag, lda, As, tid);
  stage_half(Bg, ldb, Bs, tid);
  stage_half(Ag + 32, lda, As + 8192, tid);
  stage_half(Bg + 32, ldb, Bs + 8192, tid);
  asm volatile("s_waitcnt vmcnt(4)" ::: "memory");
  __builtin_amdgcn_s_barrier();

  for (int kt = 0; kt < nkt; ++kt) {
    const int cur = kt & 1, nx = cur ^ 1;
    const unsigned short* Ab = As + cur * 16384;
    const unsigned short* Bb = Bs + cur * 16384;
    unsigned short* Asn = As + nx * 16384;
    unsigned short* Bsn = Bs + nx * 16384;
    const bool pf = (kt + 1 < nkt);
    const int knext = (kt + 1) * 64;
    bf16x8 a[4], b[4];

    // ---- P0: (mh0, ks0) ----
    read4(Ab + aoff, a);
    read4(Bb + boff, b);
    if (pf) stage_half(Ag + knext, lda, Asn, tid);
    __builtin_amdgcn_s_barrier();
    asm volatile("s_waitcnt lgkmcnt(0)" ::: "memory");
    __builtin_amdgcn_sched_barrier(0);
    __builtin_amdgcn_s_setprio(1);
    mfma16(a, b, acc, 0);
    __builtin_amdgcn_s_setprio(0);
    __builtin_amdgcn_s_barrier();

    // ---- P1: (mh1, ks0) ----
    read4(Ab + aoff + 2048, a);
    if (pf) stage_half(Bg + knext, ldb, Bsn, tid);
    __builtin_amdgcn_s_barrier();
    asm volatile("s_waitcnt lgkmcnt(0)" ::: "memory");
    __builtin_amdgcn_sched_barrier(0);
    __builtin_amdgcn_s_setprio(1);
    mfma16(a, b, acc, 1);
    __builtin_amdgcn_s_setprio(0);
    if (pf)
      asm volatile("s_waitcnt vmcnt(4)" ::: "memory");
    else
      asm volatile("s_waitcnt vmcnt(0)" ::: "memory");
    __builtin_amdgcn_s_barrier();

    // ---- P2: (mh1, ks1) ----
    read4(Ab + 8192 + aoff + 2048, a);
    read4(Bb + 8192 + boff, b);
    if (pf) stage_half(Ag + knext + 32, lda, Asn + 8192, tid);
    __builtin_amdgcn_s_barrier();
    asm volatile("s_waitcnt lgkmcnt(0)" ::: "memory");
    __builtin_amdgcn_sched_barrier(0);
    __builtin_amdgcn_s_setprio(1);
    mfma16(a, b, acc, 1);
    __builtin_amdgcn_s_setprio(0);
    __builtin_amdgcn_s_barrier();

    // ---- P3: (mh0, ks1) ----
    read4(Ab + 8192 + aoff, a);
    if (pf) stage_half(Bg + knext + 32, ldb, Bsn + 8192, tid);
    __builtin_amdgcn_s_barrier();
    asm volatile("s_waitcnt lgkmcnt(0)" ::: "memory");
    __builtin_amdgcn_sched_barrier(0);
    __builtin_amdgcn_s_setprio(1);
    mfma16(a, b, acc, 0);
    __builtin_amdgcn_s_setprio(0);
    if (pf) asm volatile("s_waitcnt vmcnt(4)" ::: "memory");
    __builtin_amdgcn_s_barrier();
  }
}

// ---------------- GEMM1: scores = qb @ kb^T (bf16 out) + row sumsq atomics ----------
__global__ __launch_bounds__(512) void gemm1_kernel(
    const unsigned short* __restrict__ A, const unsigned short* __restrict__ B,
    unsigned short* __restrict__ C, float* __restrict__ sumsq) {
  __shared__ unsigned short As[2 * 16384];
  __shared__ unsigned short Bs[2 * 16384];

  const int flat = blockIdx.y * gridDim.x + blockIdx.x;
  const int nwg  = gridDim.x * gridDim.y;
  const int swz  = (flat & 7) * (nwg >> 3) + (flat >> 3);
  const size_t m0 = (size_t)(swz / gridDim.x) * 256;
  const size_t n0 = (size_t)(swz % gridDim.x) * 256;

  f32x4 acc[8][4];
  gemm_core(A + m0 * DIN, B + n0 * DIN, DIN, DIN, DIN / 64, As, Bs, acc);

  const int tid  = threadIdx.x;
  const int lane = tid & 63;
  const int wm   = (tid >> 6) >> 2;
  const int wn   = (tid >> 6) & 3;
  const int quad = lane >> 4;
  const int l16  = lane & 15;

#pragma unroll
  for (int mf = 0; mf < 8; ++mf)
#pragma unroll
    for (int r = 0; r < 4; ++r) {
      size_t row = m0 + wm * 128 + mf * 16 + quad * 4 + r;
      float s = 0.f;
#pragma unroll
      for (int nf = 0; nf < 4; ++nf) {
        float val = acc[mf][nf][r];
        s += val * val;
        C[row * (size_t)NBANK + n0 + wn * 64 + nf * 16 + l16] = f2bf(val);
      }
      s += __shfl_xor(s, 1);
      s += __shfl_xor(s, 2);
      s += __shfl_xor(s, 4);
      s += __shfl_xor(s, 8);
      if (l16 == 0) atomicAdd(&sumsq[row], s);
    }
}

// ---------------- in-place fast GELU(x * sqrt(N/sumsq[row])) ----------------
// tanh-form: gelu(x) ~= x * sigmoid(2u), u = sqrt(2/pi)*(x + 0.044715 x^3).
// 2u = x*(1.5957691 + 0.071354816 x^2). |err vs erf-gelu| <= ~3e-4.
__global__ void gelu_kernel(unsigned short* __restrict__ S,
                            const float* __restrict__ sumsq) {
  const size_t total = (size_t)MROWS * NBANK / 8;  // uint4 units
  for (size_t u = (size_t)blockIdx.x * 256 + threadIdx.x; u < total;
       u += (size_t)gridDim.x * 256) {
    size_t idx = u * 8;
    int row = (int)(idx >> 13);
    float sc = sqrtf((float)NBANK / sumsq[row]);
    uint4 vv = *(const uint4*)(S + idx);
    unsigned int w[4] = {vv.x, vv.y, vv.z, vv.w};
#pragma unroll
    for (int e = 0; e < 4; e++) {
      float x0 = bf2f((unsigned short)(w[e] & 0xffffu)) * sc;
      float x1 = bf2f((unsigned short)(w[e] >> 16)) * sc;
      float t0 = x0 * (1.5957691f + 0.071354816f * x0 * x0);  // 2u
      float t1 = x1 * (1.5957691f + 0.071354816f * x1 * x1);
      float g0 = x0 * __builtin_amdgcn_rcpf(1.f + __expf(-t0));
      float g1 = x1 * __builtin_amdgcn_rcpf(1.f + __expf(-t1));
      w[e] = (unsigned int)f2bf(g0) | ((unsigned int)f2bf(g1) << 16);
    }
    uint4 o; o.x = w[0]; o.y = w[1]; o.z = w[2]; o.w = w[3];
    *(uint4*)(S + idx) = o;
  }
}

// ---------------- GEMM2: out = gated @ vbT^T, 128x128 tile, NO split-K --------------
// m97-class structure + both-sides LDS XOR swizzle (unchanged control arm).
__global__ __launch_bounds__(256, 4) void gemm2_kernel(
    const unsigned short* __restrict__ A,   // gated [8192][8192]
    const unsigned short* __restrict__ B,   // vbT   [1024][8192]
    float* __restrict__ C) {                // out   [8192][1024]
  __shared__ unsigned short As[128 * 32];
  __shared__ unsigned short Bs[128 * 32];
  const int K = NBANK, ldc = DOUT;

  const int tid  = threadIdx.x;
  const int lane = tid & 63;
  const int wave = tid >> 6;
  const int wm   = (wave >> 1) * 64;
  const int wn   = (wave & 1) * 64;
  const int quad = lane >> 4;
  const int l16  = lane & 15;

  const int flat = blockIdx.y * gridDim.x + blockIdx.x;
  const int nwg  = gridDim.x * gridDim.y;
  const int swz  = (flat & 7) * (nwg >> 3) + (flat >> 3);
  const size_t m0 = (size_t)(swz / gridDim.x) * 128;
  const size_t n0 = (size_t)(swz % gridDim.x) * 128;

  const int srow = tid >> 2;
  const int scol = (((tid & 3) ^ ((tid >> 3) & 3))) * 8;
  const unsigned short* Ag0 = A + (m0 + srow) * (size_t)K + scol;
  const unsigned short* Ag1 = A + (m0 + srow + 64) * (size_t)K + scol;
  const unsigned short* Bg0 = B + (n0 + srow) * (size_t)K + scol;
  const unsigned short* Bg1 = B + (n0 + srow + 64) * (size_t)K + scol;

  unsigned short* AsW0 = As + tid * 8;
  unsigned short* AsW1 = As + 64 * 32 + tid * 8;
  unsigned short* BsW0 = Bs + tid * 8;
  unsigned short* BsW1 = Bs + 64 * 32 + tid * 8;

  const int sw = (l16 >> 1) & 3;
  const unsigned short* ArP = As + (wm + l16) * 32 + (quad ^ sw) * 8;
  const unsigned short* BrP = Bs + (wn + l16) * 32 + (quad ^ sw) * 8;

  f32x4 acc[4][4];
#pragma unroll
  for (int i = 0; i < 4; i++)
#pragma unroll
    for (int j = 0; j < 4; j++) {
      f32x4 z = {0.f, 0.f, 0.f, 0.f};
      acc[i][j] = z;
    }

  for (int k0 = 0; k0 < K; k0 += 32) {
    __builtin_amdgcn_global_load_lds(
        (const __attribute__((address_space(1))) unsigned int*)(Ag0 + k0),
        (__attribute__((address_space(3))) unsigned int*)AsW0, 16, 0, 0);
    __builtin_amdgcn_global_load_lds(
        (const __attribute__((address_space(1))) unsigned int*)(Ag1 + k0),
        (__attribute__((address_space(3))) unsigned int*)AsW1, 16, 0, 0);
    __builtin_amdgcn_global_load_lds(
        (const __attribute__((address_space(1))) unsigned int*)(Bg0 + k0),
        (__attribute__((address_space(3))) unsigned int*)BsW0, 16, 0, 0);
    __builtin_amdgcn_global_load_lds(
        (const __attribute__((address_space(1))) unsigned int*)(Bg1 + k0),
        (__attribute__((address_space(3))) unsigned int*)BsW1, 16, 0, 0);
    __syncthreads();

    bf16x8 af[4], bfr[4];
#pragma unroll
    for (int i = 0; i < 4; i++) af[i] = *(const bf16x8*)(ArP + i * 16 * 32);
#pragma unroll
    for (int j = 0; j < 4; j++) bfr[j] = *(const bf16x8*)(BrP + j * 16 * 32);
#pragma unroll
    for (int i = 0; i < 4; i++)
#pragma unroll
      for (int j = 0; j < 4; j++)
        acc[i][j] = __builtin_amdgcn_mfma_f32_16x16x32_bf16(af[i], bfr[j],
                                                            acc[i][j], 0, 0, 0);
    __syncthreads();
  }

#pragma unroll
  for (int i = 0; i < 4; i++)
#pragma unroll
    for (int j = 0; j < 4; j++)
#pragma unroll
      for (int r = 0; r < 4; r++) {
        size_t row = m0 + wm + i * 16 + quad * 4 + r;
        size_t col = n0 + wn + j * 16 + l16;
        C[row * (size_t)ldc + col] = acc[i][j][r];
      }
}

extern "C" void kernel_launch(void* const* d_in, const int* in_sizes, int n_in,
                              void* d_out, int out_size, void* d_ws, size_t ws_size,
                              hipStream_t stream) {
  const float* q = (const float*)d_in[0];
  const float* k = (const float*)d_in[1];
  const float* v = (const float*)d_in[2];
  float* out = (float*)d_out;

  char* ws = (char*)d_ws;
  const size_t MB = 1024ull * 1024ull;
  unsigned short* qb     = (unsigned short*)(ws);
  unsigned short* kb     = (unsigned short*)(ws + 16 * MB);
  unsigned short* vbT    = (unsigned short*)(ws + 32 * MB);
  unsigned short* scores = (unsigned short*)(ws + 48 * MB);
  float*          scale  = (float*)(ws + 176 * MB);  // sumsq

  // 1) fused prep (cvt q, cvt k, transpose v, zero sumsq)
  prep_kernel<<<24584, 256, 0, stream>>>(q, k, v, qb, kb, vbT, scale);

  // 2) gemm1: 256^2 tiles, grid 32x32 (R5 measured-best)
  gemm1_kernel<<<dim3(NBANK / 256, MROWS / 256), 512, 0, stream>>>(qb, kb, scores,
                                                                   scale);

  // 3) gelu (tanh-form, scale folded in)
  gelu_kernel<<<4096, 256, 0, stream>>>(scores, scale);

  // 4) gemm2
  gemm2_kernel<<<dim3(DOUT / 128, MROWS / 128), 256, 0, stream>>>(scores, vbT, out);
}